// Round 15
// baseline (517.477 us; speedup 1.0000x reference)
//
#include <hip/hip_runtime.h>
#include <math.h>

#define DD 128
#define HW 512
#define MG 514

// Verified pipeline (r10/r11/r14 evidence):
//   conv: column-major taps, G1 SIMD-8 predux tree ((A+B)+(C+D))+t8
//   mag:  contract-off sqrtf(gx*gx + gy*gy)
//   cls:  comparison classifier outside 1e-4 band; fdlibm atan2f port inside

static __device__ __forceinline__ float xs_at(const float* __restrict__ xd, int a, int b) {
    if ((unsigned)(a - 1) < (unsigned)HW && (unsigned)(b - 1) < (unsigned)HW)
        return xd[(size_t)(a - 1) * HW + (b - 1)];
    return 0.0f;
}

// G1 tree, bit-identical to the r14-confirmed variant
static __device__ __forceinline__ void grad_g1(const float* __restrict__ xd, int mi, int mj,
                                               float& gx, float& gy) {
    #pragma clang fp contract(off)
    float x00=xs_at(xd,mi-1,mj-1), x01=xs_at(xd,mi-1,mj), x02=xs_at(xd,mi-1,mj+1);
    float x10=xs_at(xd,mi,mj-1),   x12=xs_at(xd,mi,mj+1);
    float x20=xs_at(xd,mi+1,mj-1), x21=xs_at(xd,mi+1,mj), x22=xs_at(xd,mi+1,mj+1);
    {
        float A = -x00;
        float B = x02 + (-x20);
        float C = 2.0f*x12;
        float D = -2.0f*x10;
        float E = A + B;
        float F = C + D;
        gx = (E + F) + x22;
    }
    {
        float A = -x00;
        float B = (-x02) + x20;
        float C = -2.0f*x01;
        float D = 2.0f*x21;
        float E = A + B;
        float F = C + D;
        gy = (E + F) + x22;
    }
}

static __device__ __forceinline__ float mag_of(float gx, float gy) {
    #pragma clang fp contract(off)
    float p = gx * gx;
    float q = gy * gy;
    return sqrtf(p + q);
}

// ---- fdlibm/glibc float atan (bit-exact port) ----
static __device__ float fd_atanf(float x) {
    #pragma clang fp contract(off)
    const unsigned hx = __float_as_uint(x);
    const unsigned ix = hx & 0x7fffffffu;
    const double A0 = 0.46364760900080611621425623146121440203;
    const double A1 = 0.78539816339744830961566084581987572105;
    const double A2 = 0.98279372324732906798571061101466601449;
    const double A3 = 1.57079632679489661923132169163975144210;
    const float aT0 =  3.3333328366e-01f;
    const float aT1 = -1.9999158382e-01f;
    const float aT2 =  1.4253635705e-01f;
    const float aT3 = -1.0648017377e-01f;
    const float aT4 =  6.1687607318e-02f;
    float z, w, s1, s2;
    int id;
    double a;
    if (ix >= 0x4c800000u) {
        a = A3;
        float hi = (float)a; if ((double)hi > a) hi = __uint_as_float(__float_as_uint(hi) - 1u);
        float lo = (float)(a - (double)hi);
        float r = hi + lo;
        return (hx >> 31) ? -r : r;
    }
    if (ix < 0x3ee00000u) {
        if (ix < 0x39800000u) return x;
        id = -1;
    } else {
        x = fabsf(x);
        if (ix < 0x3f980000u) {
            if (ix < 0x3f300000u) { id = 0; x = (2.0f * x - 1.0f) / (2.0f + x); }
            else                  { id = 1; x = (x - 1.0f) / (x + 1.0f); }
        } else {
            if (ix < 0x401c0000u) { id = 2; x = (x - 1.5f) / (1.0f + 1.5f * x); }
            else                  { id = 3; x = -1.0f / x; }
        }
    }
    z = x * x;
    w = z * z;
    s1 = z * (aT0 + w * (aT2 + w * aT4));
    s2 = w * (aT1 + w * aT3);
    if (id < 0) return x - x * (s1 + s2);
    a = (id == 0) ? A0 : (id == 1) ? A1 : (id == 2) ? A2 : A3;
    float hi = (float)a; if ((double)hi > a) hi = __uint_as_float(__float_as_uint(hi) - 1u);
    float lo = (float)(a - (double)hi);
    z = hi - ((x * (s1 + s2) - lo) - x);
    return (hx >> 31) ? -z : z;
}

static __device__ int cls_fd(float y, float x) {
    #pragma clang fp contract(off)
    const unsigned hx = __float_as_uint(x), hy = __float_as_uint(y);
    const unsigned ix = hx & 0x7fffffffu, iy = hy & 0x7fffffffu;
    unsigned m = ((hy >> 31) & 1u) | ((hx >> 30) & 2u);
    const double PI_D = 3.14159265358979323846264338327950288420;
    const float pi_f  = (float)PI_D;
    const float pi_lo = (float)(PI_D - (double)pi_f);
    const float pi4_f = (float)(PI_D / 4.0);
    const float pi2_f = (float)(PI_D / 2.0);
    float v;
    if (iy == 0) {
        v = (m == 0 || m == 1) ? y : (m == 2 ? pi_f : -pi_f);
    } else if (ix == 0) {
        v = (m & 1u) ? -pi2_f : pi2_f;
    } else if (ix + (26u << 23) < iy) {
        v = (m & 1u) ? -pi2_f : pi2_f;
    } else {
        float z;
        if ((m & 2u) && iy + (26u << 23) < ix) z = 0.0f;
        else z = fd_atanf(fabsf(y / x));
        switch (m) {
            case 0:  v = z; break;
            case 1:  v = -z; break;
            case 2:  v = pi_f - (z - pi_lo); break;
            default: v = (z - pi_lo) - pi_f; break;
        }
    }
    float t = v / pi4_f;
    int n = (int)rintf(t);
    return n & 3;
}

static __device__ __forceinline__ int classify(float gx, float gy) {
    #pragma clang fp contract(off)
    float ax = fabsf(gx), ay = fabsf(gy);
    const float T = 0.41421356237309504880f;   // tan(pi/8)
    float r1 = ay - ax * T;
    float r2 = ax - ay * T;
    float eps = 1e-4f * (ax + ay);
    if (fabsf(r1) > eps && fabsf(r2) > eps) {
        if (r1 < 0.0f) return 0;
        if (r2 < 0.0f) return 2;
        return ((__float_as_uint(gx) ^ __float_as_uint(gy)) >> 31) ? 3 : 1;
    }
    return cls_fd(gy, gx);
}

// ---------------- Pass 1: per-slice post-NMS max ----------------
__global__ __launch_bounds__(256) void k_max(const float* __restrict__ x,
                                             unsigned int* __restrict__ smax) {
    __shared__ float         mag_s[18][67];
    __shared__ unsigned char cls_s[18][67];
    const int d  = blockIdx.z;
    const int i0 = blockIdx.y * 16;
    const int j0 = blockIdx.x * 64;
    const float* xd = x + (size_t)d * HW * HW;
    const int t = threadIdx.y * 64 + threadIdx.x;

    for (int idx = t; idx < 18 * 66; idx += 256) {
        int r = idx / 66, c = idx - r * 66;
        int mi = (i0 - 1 + r + MG) % MG;   // jnp.roll wrap for halo
        int mj = (j0 - 1 + c + MG) % MG;
        float gx, gy;
        grad_g1(xd, mi, mj, gx, gy);
        mag_s[r][c] = mag_of(gx, gy);
        cls_s[r][c] = (unsigned char)classify(gx, gy);
    }
    __syncthreads();

    float tmax = 0.0f;
    #pragma unroll
    for (int qq = 0; qq < 4; ++qq) {
        int ry = threadIdx.y + 4 * qq;
        int gi = i0 + ry, gj = j0 + threadIdx.x;
        if (gi < MG && gj < MG) {
            int r = ry + 1, c = threadIdx.x + 1;
            float m = mag_s[r][c]; int cl = cls_s[r][c]; float a, b;
            if (cl == 0)      { a = mag_s[r][c-1];   b = mag_s[r][c+1];   }
            else if (cl == 1) { a = mag_s[r-1][c-1]; b = mag_s[r+1][c+1]; }
            else if (cl == 2) { a = mag_s[r-1][c];   b = mag_s[r+1][c];   }
            else              { a = mag_s[r-1][c+1]; b = mag_s[r+1][c-1]; }
            if (m >= a && m >= b) tmax = fmaxf(tmax, m);
        }
    }
    for (int off = 32; off > 0; off >>= 1)
        tmax = fmaxf(tmax, __shfl_down(tmax, off, 64));
    __shared__ float wmax[4];
    if ((t & 63) == 0) wmax[t >> 6] = tmax;
    __syncthreads();
    if (t == 0) {
        float bm = fmaxf(fmaxf(wmax[0], wmax[1]), fmaxf(wmax[2], wmax[3]));
        atomicMax(smax + d, __float_as_uint(bm));  // mags >= 0: uint order-preserving
    }
}

// ---------------- Pass 2: recompute + NMS + hysteresis + crop ----------------
__global__ __launch_bounds__(256) void k_edges(const float* __restrict__ x,
                                               const unsigned int* __restrict__ smax,
                                               float* __restrict__ out) {
    __shared__ float         mag2[20][69];
    __shared__ unsigned char cls2[20][69];
    __shared__ float         nms2[18][67];
    const int d   = blockIdx.z;
    const int ys  = blockIdx.y * 16;
    const int xs0 = blockIdx.x * 64;
    const int gi0 = ys + 1, gj0 = xs0 + 1;
    const float* xd = x + (size_t)d * HW * HW;
    const int t = threadIdx.y * 64 + threadIdx.x;

    for (int idx = t; idx < 20 * 68; idx += 256) {
        int r = idx / 68, c = idx - r * 68;
        int mi = (gi0 - 2 + r + MG) % MG;
        int mj = (gj0 - 2 + c + MG) % MG;
        float gx, gy;
        grad_g1(xd, mi, mj, gx, gy);
        mag2[r][c] = mag_of(gx, gy);
        cls2[r][c] = (unsigned char)classify(gx, gy);
    }
    __syncthreads();

    for (int idx = t; idx < 18 * 66; idx += 256) {
        int r = idx / 66, c = idx - r * 66;
        int rr = r + 1, cc = c + 1;
        float m = mag2[rr][cc]; int cl = cls2[rr][cc]; float a, b;
        if (cl == 0)      { a = mag2[rr][cc-1];   b = mag2[rr][cc+1];   }
        else if (cl == 1) { a = mag2[rr-1][cc-1]; b = mag2[rr+1][cc+1]; }
        else if (cl == 2) { a = mag2[rr-1][cc];   b = mag2[rr+1][cc];   }
        else              { a = mag2[rr-1][cc+1]; b = mag2[rr+1][cc-1]; }
        nms2[r][c] = (m >= a && m >= b) ? m : 0.0f;
    }
    __syncthreads();

    const float high = __uint_as_float(smax[d]) * 0.05f;
    const float low  = high * 0.01f;

    #pragma unroll
    for (int qq = 0; qq < 4; ++qq) {
        int ry = threadIdx.y + 4 * qq;
        int y  = ys + ry, xo = xs0 + threadIdx.x;
        int r  = ry + 1,  c  = threadIdx.x + 1;
        float m = nms2[r][c];
        float e;
        if (m >= high) {
            e = 1.0f;
        } else if (m >= low) {
            bool pooled =
                nms2[r-1][c-1] >= high || nms2[r-1][c] >= high || nms2[r-1][c+1] >= high ||
                nms2[r][c-1]   >= high ||                         nms2[r][c+1]   >= high ||
                nms2[r+1][c-1] >= high || nms2[r+1][c] >= high || nms2[r+1][c+1] >= high;
            e = pooled ? 1.0f : 0.0f;
        } else {
            e = 0.0f;
        }
        out[((size_t)d * HW + y) * HW + xo] = e;
    }
}

extern "C" void kernel_launch(void* const* d_in, const int* in_sizes, int n_in,
                              void* d_out, int out_size, void* d_ws, size_t ws_size,
                              hipStream_t stream) {
    const float* x = (const float*)d_in[0];
    float* out = (float*)d_out;
    unsigned int* smax = (unsigned int*)d_ws;   // 128 * 4B

    hipMemsetAsync(smax, 0, DD * sizeof(unsigned int), stream);

    dim3 blk(64, 4, 1);
    k_max  <<<dim3(9, 33, DD), blk, 0, stream>>>(x, smax);
    k_edges<<<dim3(8, 32, DD), blk, 0, stream>>>(x, smax, out);
}

// Round 16
// 389.334 us; speedup vs baseline: 1.3291x; 1.3291x over previous
//
#include <hip/hip_runtime.h>
#include <math.h>

#define DD 128
#define HW 512
#define MG 514

// Verified reference stack (r10/r11/r14): G1 predux-tree colmajor conv,
// contract-off mul/add mag, fd-hybrid classifier. This round: perf refactor
// (LDS staging + single compute pass + NMS spill to ws), bit-identical math.

// ---- G1 tree conv from LDS-staged x values (bit-identical arithmetic) ----
static __device__ __forceinline__ void grad_g1_lds(const float xs[20][69], int r, int c,
                                                   float& gx, float& gy) {
    #pragma clang fp contract(off)
    float x00 = xs[r][c],     x01 = xs[r][c+1],   x02 = xs[r][c+2];
    float x10 = xs[r+1][c],                       x12 = xs[r+1][c+2];
    float x20 = xs[r+2][c],   x21 = xs[r+2][c+1], x22 = xs[r+2][c+2];
    {
        float A = -x00;
        float B = x02 + (-x20);
        float C = 2.0f*x12;
        float D = -2.0f*x10;
        float E = A + B;
        float F = C + D;
        gx = (E + F) + x22;
    }
    {
        float A = -x00;
        float B = (-x02) + x20;
        float C = -2.0f*x01;
        float D = 2.0f*x21;
        float E = A + B;
        float F = C + D;
        gy = (E + F) + x22;
    }
}

static __device__ __forceinline__ float mag_of(float gx, float gy) {
    #pragma clang fp contract(off)
    float p = gx * gx;
    float q = gy * gy;
    return sqrtf(p + q);
}

// ---- fdlibm/glibc float atan (bit-exact port) ----
static __device__ float fd_atanf(float x) {
    #pragma clang fp contract(off)
    const unsigned hx = __float_as_uint(x);
    const unsigned ix = hx & 0x7fffffffu;
    const double A0 = 0.46364760900080611621425623146121440203;
    const double A1 = 0.78539816339744830961566084581987572105;
    const double A2 = 0.98279372324732906798571061101466601449;
    const double A3 = 1.57079632679489661923132169163975144210;
    const float aT0 =  3.3333328366e-01f;
    const float aT1 = -1.9999158382e-01f;
    const float aT2 =  1.4253635705e-01f;
    const float aT3 = -1.0648017377e-01f;
    const float aT4 =  6.1687607318e-02f;
    float z, w, s1, s2;
    int id;
    double a;
    if (ix >= 0x4c800000u) {
        a = A3;
        float hi = (float)a; if ((double)hi > a) hi = __uint_as_float(__float_as_uint(hi) - 1u);
        float lo = (float)(a - (double)hi);
        float r = hi + lo;
        return (hx >> 31) ? -r : r;
    }
    if (ix < 0x3ee00000u) {
        if (ix < 0x39800000u) return x;
        id = -1;
    } else {
        x = fabsf(x);
        if (ix < 0x3f980000u) {
            if (ix < 0x3f300000u) { id = 0; x = (2.0f * x - 1.0f) / (2.0f + x); }
            else                  { id = 1; x = (x - 1.0f) / (x + 1.0f); }
        } else {
            if (ix < 0x401c0000u) { id = 2; x = (x - 1.5f) / (1.0f + 1.5f * x); }
            else                  { id = 3; x = -1.0f / x; }
        }
    }
    z = x * x;
    w = z * z;
    s1 = z * (aT0 + w * (aT2 + w * aT4));
    s2 = w * (aT1 + w * aT3);
    if (id < 0) return x - x * (s1 + s2);
    a = (id == 0) ? A0 : (id == 1) ? A1 : (id == 2) ? A2 : A3;
    float hi = (float)a; if ((double)hi > a) hi = __uint_as_float(__float_as_uint(hi) - 1u);
    float lo = (float)(a - (double)hi);
    z = hi - ((x * (s1 + s2) - lo) - x);
    return (hx >> 31) ? -z : z;
}

static __device__ int cls_fd(float y, float x) {
    #pragma clang fp contract(off)
    const unsigned hx = __float_as_uint(x), hy = __float_as_uint(y);
    const unsigned ix = hx & 0x7fffffffu, iy = hy & 0x7fffffffu;
    unsigned m = ((hy >> 31) & 1u) | ((hx >> 30) & 2u);
    const double PI_D = 3.14159265358979323846264338327950288420;
    const float pi_f  = (float)PI_D;
    const float pi_lo = (float)(PI_D - (double)pi_f);
    const float pi4_f = (float)(PI_D / 4.0);
    const float pi2_f = (float)(PI_D / 2.0);
    float v;
    if (iy == 0) {
        v = (m == 0 || m == 1) ? y : (m == 2 ? pi_f : -pi_f);
    } else if (ix == 0) {
        v = (m & 1u) ? -pi2_f : pi2_f;
    } else if (ix + (26u << 23) < iy) {
        v = (m & 1u) ? -pi2_f : pi2_f;
    } else {
        float z;
        if ((m & 2u) && iy + (26u << 23) < ix) z = 0.0f;
        else z = fd_atanf(fabsf(y / x));
        switch (m) {
            case 0:  v = z; break;
            case 1:  v = -z; break;
            case 2:  v = pi_f - (z - pi_lo); break;
            default: v = (z - pi_lo) - pi_f; break;
        }
    }
    float t = v / pi4_f;
    int n = (int)rintf(t);
    return n & 3;
}

static __device__ __forceinline__ int classify(float gx, float gy) {
    #pragma clang fp contract(off)
    float ax = fabsf(gx), ay = fabsf(gy);
    const float T = 0.41421356237309504880f;   // tan(pi/8)
    float r1 = ay - ax * T;
    float r2 = ax - ay * T;
    float eps = 1e-4f * (ax + ay);
    if (fabsf(r1) > eps && fabsf(r2) > eps) {
        if (r1 < 0.0f) return 0;
        if (r2 < 0.0f) return 2;
        return ((__float_as_uint(gx) ^ __float_as_uint(gy)) >> 31) ? 3 : 1;
    }
    return cls_fd(gy, gx);
}

// ---------- k1: stage x -> mag/cls -> NMS -> (nms to ws, per-slice max) ----------
__global__ __launch_bounds__(256) void k_nms(const float* __restrict__ x,
                                             float* __restrict__ nms,
                                             unsigned int* __restrict__ smax) {
    __shared__ float         xs[20][69];
    __shared__ float         mag_s[18][67];
    __shared__ unsigned char cls_s[18][67];
    const int d  = blockIdx.z;
    const int i0 = blockIdx.y * 16;
    const int j0 = blockIdx.x * 64;
    const float* xd = x + (size_t)d * HW * HW;
    const int t = threadIdx.y * 64 + threadIdx.x;

    // stage x region: grid rows i0-2..i0+17, cols j0-2..j0+65 (wrap + zero ring)
    for (int idx = t; idx < 20 * 68; idx += 256) {
        int rr = idx / 68, cc = idx - rr * 68;
        int gr = i0 - 2 + rr;  gr += (gr < 0) ? MG : 0;  gr -= (gr >= MG) ? MG : 0;
        int gc = j0 - 2 + cc;  gc += (gc < 0) ? MG : 0;  gc -= (gc >= MG) ? MG : 0;
        float v = 0.0f;
        if ((unsigned)(gr - 1) < (unsigned)HW && (unsigned)(gc - 1) < (unsigned)HW)
            v = xd[(size_t)(gr - 1) * HW + (gc - 1)];
        xs[rr][cc] = v;
    }
    __syncthreads();

    // mag/cls for 18x66 halo tile (grid rows i0-1.., cols j0-1..)
    for (int idx = t; idx < 18 * 66; idx += 256) {
        int r = idx / 66, c = idx - r * 66;
        float gx, gy;
        grad_g1_lds(xs, r, c, gx, gy);
        mag_s[r][c] = mag_of(gx, gy);
        cls_s[r][c] = (unsigned char)classify(gx, gy);
    }
    __syncthreads();

    // NMS for 16x64 interior; write to global nms; track per-thread max
    float tmax = 0.0f;
    #pragma unroll
    for (int qq = 0; qq < 4; ++qq) {
        int ry = threadIdx.y + 4 * qq;
        int gi = i0 + ry, gj = j0 + threadIdx.x;
        if (gi < MG && gj < MG) {
            int r = ry + 1, c = threadIdx.x + 1;
            float m = mag_s[r][c]; int cl = cls_s[r][c]; float a, b;
            if (cl == 0)      { a = mag_s[r][c-1];   b = mag_s[r][c+1];   }
            else if (cl == 1) { a = mag_s[r-1][c-1]; b = mag_s[r+1][c+1]; }
            else if (cl == 2) { a = mag_s[r-1][c];   b = mag_s[r+1][c];   }
            else              { a = mag_s[r-1][c+1]; b = mag_s[r+1][c-1]; }
            float v = (m >= a && m >= b) ? m : 0.0f;
            nms[((size_t)d * MG + gi) * MG + gj] = v;
            tmax = fmaxf(tmax, v);
        }
    }
    for (int off = 32; off > 0; off >>= 1)
        tmax = fmaxf(tmax, __shfl_down(tmax, off, 64));
    __shared__ float wmax[4];
    if ((t & 63) == 0) wmax[t >> 6] = tmax;
    __syncthreads();
    if (t == 0) {
        float bm = fmaxf(fmaxf(wmax[0], wmax[1]), fmaxf(wmax[2], wmax[3]));
        atomicMax(smax + d, __float_as_uint(bm));  // nonneg: uint order-preserving
    }
}

// ---------- k2: thresholds + 3x3 strong-pool hysteresis + crop ----------
__global__ __launch_bounds__(256) void k_edges(const float* __restrict__ nms,
                                               const unsigned int* __restrict__ smax,
                                               float* __restrict__ out) {
    __shared__ float ns[18][67];
    const int d   = blockIdx.z;
    const int ys  = blockIdx.y * 16;       // output row origin
    const int xs0 = blockIdx.x * 64;       // output col origin
    const float* nd = nms + (size_t)d * MG * MG;
    const int t = threadIdx.y * 64 + threadIdx.x;

    // stage nms grid rows ys..ys+17, cols xs0..xs0+65 (= grid coords of out-1 .. out+16)
    for (int idx = t; idx < 18 * 66; idx += 256) {
        int r = idx / 66, c = idx - r * 66;
        ns[r][c] = nd[(size_t)(ys + r) * MG + (xs0 + c)];
    }
    __syncthreads();

    const float high = __uint_as_float(smax[d]) * 0.05f;
    const float low  = high * 0.01f;

    #pragma unroll
    for (int qq = 0; qq < 4; ++qq) {
        int ry = threadIdx.y + 4 * qq;
        int y  = ys + ry, xo = xs0 + threadIdx.x;
        int r  = ry + 1,  c  = threadIdx.x + 1;
        float m = ns[r][c];
        float e;
        if (m >= high) {
            e = 1.0f;
        } else if (m >= low) {
            bool pooled =
                ns[r-1][c-1] >= high || ns[r-1][c] >= high || ns[r-1][c+1] >= high ||
                ns[r][c-1]   >= high ||                       ns[r][c+1]   >= high ||
                ns[r+1][c-1] >= high || ns[r+1][c] >= high || ns[r+1][c+1] >= high;
            e = pooled ? 1.0f : 0.0f;
        } else {
            e = 0.0f;
        }
        out[((size_t)d * HW + y) * HW + xo] = e;
    }
}

extern "C" void kernel_launch(void* const* d_in, const int* in_sizes, int n_in,
                              void* d_out, int out_size, void* d_ws, size_t ws_size,
                              hipStream_t stream) {
    const float* x = (const float*)d_in[0];
    float* out = (float*)d_out;
    float* nms = (float*)d_ws;                                   // 514*514*128*4 = 135.26 MB
    unsigned int* smax = (unsigned int*)((char*)d_ws + (size_t)DD * MG * MG * sizeof(float));

    hipMemsetAsync(smax, 0, DD * sizeof(unsigned int), stream);

    dim3 blk(64, 4, 1);
    k_nms  <<<dim3(9, 33, DD), blk, 0, stream>>>(x, nms, smax);  // full 514 grid
    k_edges<<<dim3(8, 32, DD), blk, 0, stream>>>(nms, smax, out);
}